// Round 3
// baseline (436.105 us; speedup 1.0000x reference)
//
#include <hip/hip_runtime.h>

// FFTConvNet: out[b,o] = IFFT2( M · sum_i X^[(b+8)%16, i] · W^[(o+32)%64, i] ) + bias[o]
// fftshift(no axes) shifts ALL dims -> batch roll 8, Cout roll 32; Cin rolls cancel.
// Disk mask fy^2+fx^2<=900. Hermitian half-spectrum: fy in [0,30] (31), fx in [-30,30] (61), NF=1891.
// Axis-swapped pipeline (column DFT first => stage 1 fully coalesced, no LDS):
//   k1': X1[bi][c=2t+ri][x] = sum_y img[y][x] e^{-2pi i t y/128},  t=fy 0..30
//   k2': X2[bi][f'=t*61+fxp] = mask * sum_x X1_t(x) e^{-2pi i (fxp-30) x/128}
//   k3 : F[f'][b*64+o] = sum_i X2[(b+8)&15, i][f'] * W^[(o+32)&63, i][f']
//   k4': H[((fy*16+b)*64+o)][x] = sum_fxp F[fy*61+fxp][bo] e^{+2pi i (fxp-30) x/128}
//   k5': out[b][o][y][x] = sum_c T[c][y] * D[c][x] + bias   (Hermitian fold over fy)
// ws floats: X1 8,126,464 ; X2 3,872,768 ; F 3,872,768 ; H reuses X1 region.

#define PI2_128 0.04908738521234052f  // 2*pi/128
#define NF 1891                       // 31*61

// ---------------- K1': column DFT, no LDS, coalesced ----------------
__global__ __launch_bounds__(256) void k1_coldft(const float* __restrict__ x,
                                                 float* __restrict__ X1) {
  const int bi = blockIdx.x;
  const int tid = threadIdx.x;
  const int tg = tid >> 4;   // 0..15 -> t0 = 2*tg (t = fy)
  const int xg = tid & 15;   // 0..15 -> x0 = 8*xg
  const int t0 = tg * 2;
  const int x0 = xg * 8;
  const float* img = x + (size_t)bi * (128 * 128);

  float pc[2], ps[2], stc[2], sts[2];
#pragma unroll
  for (int f = 0; f < 2; ++f) {
    __sincosf((float)(t0 + f) * PI2_128, &sts[f], &stc[f]);
    pc[f] = 1.f;
    ps[f] = 0.f;
  }
  float o_r[2][8] = {{0.f}}, o_i[2][8] = {{0.f}};
  for (int y = 0; y < 128; ++y) {
    float4 v0 = *(const float4*)(img + y * 128 + x0);
    float4 v1 = *(const float4*)(img + y * 128 + x0 + 4);
    float vv[8] = {v0.x, v0.y, v0.z, v0.w, v1.x, v1.y, v1.z, v1.w};
#pragma unroll
    for (int f = 0; f < 2; ++f) {
      float c = pc[f], s = ps[f];
#pragma unroll
      for (int j = 0; j < 8; ++j) {
        o_r[f][j] += vv[j] * c;
        o_i[f][j] -= vv[j] * s;
      }
      pc[f] = c * stc[f] - s * sts[f];
      ps[f] = s * stc[f] + c * sts[f];
    }
  }
  float* X1s = X1 + (size_t)bi * (62 * 128);
#pragma unroll
  for (int f = 0; f < 2; ++f) {
    int t = t0 + f;
    if (t < 31) {
      *(float4*)(X1s + (2 * t) * 128 + x0) = make_float4(o_r[f][0], o_r[f][1], o_r[f][2], o_r[f][3]);
      *(float4*)(X1s + (2 * t) * 128 + x0 + 4) = make_float4(o_r[f][4], o_r[f][5], o_r[f][6], o_r[f][7]);
      *(float4*)(X1s + (2 * t + 1) * 128 + x0) = make_float4(o_i[f][0], o_i[f][1], o_i[f][2], o_i[f][3]);
      *(float4*)(X1s + (2 * t + 1) * 128 + x0 + 4) = make_float4(o_i[f][4], o_i[f][5], o_i[f][6], o_i[f][7]);
    }
  }
}

// ---------------- K2': row DFT + disk mask ----------------
__global__ __launch_bounds__(256) void k2_rowdft(const float* __restrict__ X1,
                                                 float* __restrict__ X2) {
  __shared__ __align__(16) float Bl[128 * 68];  // [x][c], stride 68
  const int bi = blockIdx.x;
  const int tid = threadIdx.x;
  const float* X1s = X1 + (size_t)bi * (62 * 128);
  for (int j = tid; j < 62 * 32; j += 256) {
    int c = j >> 5, xq = j & 31;
    float4 v = *(const float4*)(X1s + c * 128 + xq * 4);
    float vv[4] = {v.x, v.y, v.z, v.w};
#pragma unroll
    for (int u = 0; u < 4; ++u) Bl[(xq * 4 + u) * 68 + c] = vv[u];
  }
  __syncthreads();
  const int tg = tid >> 5;   // 0..7  -> t0 = 4*tg
  const int fxg = tid & 31;  // 0..31 -> fxp0 = 2*fxg
  const int t0 = tg * 4;
  const int fxp0 = fxg * 2;

  float pc[2], ps[2], stc[2], sts[2];
#pragma unroll
  for (int j = 0; j < 2; ++j) {
    float fx = (float)(fxp0 + j - 30);
    __sincosf(fx * PI2_128, &sts[j], &stc[j]);
    pc[j] = 1.f;
    ps[j] = 0.f;
  }
  float o_r[4][2] = {{0.f}}, o_i[4][2] = {{0.f}};
  for (int xx = 0; xx < 128; ++xx) {
    float4 a0 = *(const float4*)(&Bl[xx * 68 + 8 * tg]);
    float4 a1 = *(const float4*)(&Bl[xx * 68 + 8 * tg + 4]);
    float ar[4] = {a0.x, a0.z, a1.x, a1.z};
    float ai[4] = {a0.y, a0.w, a1.y, a1.w};
#pragma unroll
    for (int j = 0; j < 2; ++j) {
      float c = pc[j], s = ps[j];
#pragma unroll
      for (int tt = 0; tt < 4; ++tt) {
        o_r[tt][j] += ar[tt] * c + ai[tt] * s;
        o_i[tt][j] += ai[tt] * c - ar[tt] * s;
      }
      pc[j] = c * stc[j] - s * sts[j];
      ps[j] = s * stc[j] + c * sts[j];
    }
  }
  float2* X2c = (float2*)X2 + (size_t)bi * NF;
#pragma unroll
  for (int tt = 0; tt < 4; ++tt) {
    int t = t0 + tt;
    if (t >= 31) continue;
#pragma unroll
    for (int j = 0; j < 2; ++j) {
      int fxp = fxp0 + j;
      if (fxp >= 61) continue;
      int fx = fxp - 30;
      bool keep = (t * t + fx * fx) <= 900;
      X2c[t * 61 + fxp] = keep ? make_float2(o_r[tt][j], o_i[tt][j]) : make_float2(0.f, 0.f);
    }
  }
}

// ---------------- K3: per-frequency channel mix (f-tile 2) ----------------
__global__ __launch_bounds__(256) void k3_mix(const float* __restrict__ X2,
                                              const float* __restrict__ w,
                                              float* __restrict__ F) {
  __shared__ float2 tw[128];
  __shared__ __align__(16) float2 X2t[2][16][16];  // [fi][il][b]
  __shared__ __align__(16) float2 Wt[2][16][64];   // [fi][il][o]
  const int tid = threadIdx.x;
  const int f0 = blockIdx.x * 2;
  if (tid < 128) {
    float sv, cv;
    __sincosf((float)tid * PI2_128, &sv, &cv);
    tw[tid] = make_float2(cv, sv);
  }
  const int fi_g = tid >> 7;  // 0..1
  const int lane = tid & 127;
  const int bt = lane >> 4;  // 0..7  -> b0 = 2*bt
  const int ot = lane & 15;  // 0..15 -> o0 = 4*ot
  const int fg = f0 + fi_g;
  float o_r[2][4] = {{0.f}}, o_i[2][4] = {{0.f}};
  __syncthreads();

  for (int itile = 0; itile < 4; ++itile) {
    for (int j = tid; j < 512; j += 256) {  // 2 f * 16 i * 16 b
      int fi = j >> 8, rem = j & 255;
      int il = rem >> 4, b = rem & 15;
      int f = f0 + fi;
      if (f < NF) {
        int i = itile * 16 + il;
        int bs = (b + 8) & 15;  // batch fftshift
        X2t[fi][il][b] = ((const float2*)X2)[(size_t)(bs * 64 + i) * NF + f];
      }
    }
    for (int j = tid; j < 2048; j += 256) {  // 2 f * 16 i * 64 o
      int fi = j >> 10, rem = j & 1023;
      int il = rem >> 6, o = rem & 63;
      int f = f0 + fi;
      if (f < NF) {
        int fy = f / 61;
        int fx = (f - fy * 61) - 30;
        int i = itile * 16 + il;
        int op = (o + 32) & 63;  // Cout fftshift
        const float* wp = w + (size_t)(op * 64 + i) * 9;
        float re = 0.f, im = 0.f;
#pragma unroll
        for (int ky = 0; ky < 3; ++ky)
#pragma unroll
          for (int kx = 0; kx < 3; ++kx) {
            int m = (fy * ky + fx * kx) & 127;
            float wv = wp[ky * 3 + kx];
            re += wv * tw[m].x;
            im -= wv * tw[m].y;
          }
        Wt[fi][il][o] = make_float2(re, im);
      }
    }
    __syncthreads();
    for (int il = 0; il < 16; ++il) {
      float2 xv[2], wv[4];
#pragma unroll
      for (int jb = 0; jb < 2; ++jb) xv[jb] = X2t[fi_g][il][bt * 2 + jb];
#pragma unroll
      for (int jo = 0; jo < 4; ++jo) wv[jo] = Wt[fi_g][il][ot * 4 + jo];
#pragma unroll
      for (int jb = 0; jb < 2; ++jb)
#pragma unroll
        for (int jo = 0; jo < 4; ++jo) {
          o_r[jb][jo] += xv[jb].x * wv[jo].x - xv[jb].y * wv[jo].y;
          o_i[jb][jo] += xv[jb].x * wv[jo].y + xv[jb].y * wv[jo].x;
        }
    }
    __syncthreads();
  }
  if (fg < NF) {
    float2* Fc = (float2*)F + (size_t)fg * 1024;
#pragma unroll
    for (int jb = 0; jb < 2; ++jb) {
      int b = bt * 2 + jb;
#pragma unroll
      for (int jo = 0; jo < 4; ++jo)
        Fc[b * 64 + ot * 4 + jo] = make_float2(o_r[jb][jo], o_i[jb][jo]);
    }
  }
}

// ---------------- K4': inverse row DFT ----------------
// H[((fy*16+b)*64+o)][x] = sum_{fxp} F[fy*61+fxp][bo] e^{+2pi i (fxp-30) x/128}
__global__ __launch_bounds__(256) void k4_invrow(const float* __restrict__ F,
                                                 float* __restrict__ H) {
  __shared__ __align__(16) float2 Fl[61][32];  // [fxp][bo-local]
  const int fy = blockIdx.x >> 5;        // 0..30
  const int bo0 = (blockIdx.x & 31) * 32;
  const int tid = threadIdx.x;
  const float2* Fc = (const float2*)F;
  for (int j = tid; j < 61 * 16; j += 256) {
    int c = j >> 4, bp = j & 15;
    float4 v = *(const float4*)(Fc + (size_t)(fy * 61 + c) * 1024 + bo0 + 2 * bp);
    Fl[c][2 * bp] = make_float2(v.x, v.y);
    Fl[c][2 * bp + 1] = make_float2(v.z, v.w);
  }
  __syncthreads();
  const int bog = tid >> 4;  // 0..15 -> 2 bo each
  const int xg = tid & 15;   // 0..15 -> x0 = 8*xg
  const int x0 = xg * 8;

  float pc[8], ps[8], stc[8], sts[8];
#pragma unroll
  for (int u = 0; u < 8; ++u) {
    int xx = x0 + u;
    __sincosf((float)xx * PI2_128, &sts[u], &stc[u]);  // step e^{+2pi i x/128}
    int m = (-30 * xx) & 127;                          // init at fx=-30
    __sincosf((float)m * PI2_128, &ps[u], &pc[u]);
  }
  float g_r[2][8] = {{0.f}}, g_i[2][8] = {{0.f}};
  for (int c = 0; c < 61; ++c) {
    float4 fv = *(const float4*)(&Fl[c][2 * bog]);
    float fr[2] = {fv.x, fv.z}, fim[2] = {fv.y, fv.w};
#pragma unroll
    for (int u = 0; u < 8; ++u) {
      float cc = pc[u], ss = ps[u];
#pragma unroll
      for (int v = 0; v < 2; ++v) {
        g_r[v][u] += fr[v] * cc - fim[v] * ss;
        g_i[v][u] += fr[v] * ss + fim[v] * cc;
      }
      pc[u] = cc * stc[u] - ss * sts[u];
      ps[u] = ss * stc[u] + cc * sts[u];
    }
  }
  float2* Hc = (float2*)H;
#pragma unroll
  for (int v = 0; v < 2; ++v) {
    int bo = bo0 + 2 * bog + v;
    size_t base = (size_t)((fy * 16 + (bo >> 6)) * 64 + (bo & 63)) * 128 + x0;
#pragma unroll
    for (int u = 0; u < 8; u += 2) {
      *(float4*)(&Hc[base + u]) = make_float4(g_r[v][u], g_i[v][u], g_r[v][u + 1], g_i[v][u + 1]);
    }
  }
}

// ---------------- K5': inverse column DFT (Hermitian) + bias ----------------
__global__ __launch_bounds__(256) void k5_invcol(const float* __restrict__ H,
                                                 const float* __restrict__ bias,
                                                 float* __restrict__ out) {
  __shared__ __align__(16) float D[61 * 128];  // [c][x]
  __shared__ __align__(16) float T[61 * 64];   // [c][y-local]
  const int yh = blockIdx.x & 1;
  const int o = (blockIdx.x >> 1) & 63;
  const int b = blockIdx.x >> 7;
  const int tid = threadIdx.x;
  const float2* Hc = (const float2*)H;
  for (int j = tid; j < 31 * 64; j += 256) {
    int fy = j >> 6, xp = j & 63;
    float4 v = *(const float4*)(Hc + (size_t)((fy * 16 + b) * 64 + o) * 128 + 2 * xp);
    D[fy * 128 + 2 * xp] = v.x;
    D[fy * 128 + 2 * xp + 1] = v.z;
    if (fy >= 1) {
      D[(30 + fy) * 128 + 2 * xp] = v.y;
      D[(30 + fy) * 128 + 2 * xp + 1] = v.w;
    }
  }
  const float sc1 = 1.f / 16384.f;
  for (int j = tid; j < 61 * 64; j += 256) {
    int c = j >> 6, yy = j & 63;
    int y = yh * 64 + yy;
    float val;
    if (c == 0) {
      val = sc1;
    } else if (c <= 30) {
      int m = (c * y) & 127;
      float sv, cv;
      __sincosf((float)m * PI2_128, &sv, &cv);
      val = 2.f * sc1 * cv;
    } else {
      int m = ((c - 30) * y) & 127;
      float sv, cv;
      __sincosf((float)m * PI2_128, &sv, &cv);
      val = -2.f * sc1 * sv;
    }
    T[c * 64 + yy] = val;
  }
  __syncthreads();
  const int yg = tid >> 4, xg = tid & 15;
  const int yy0 = yg * 4, x0 = xg * 8;
  float acc[4][8] = {{0.f}};
  for (int c = 0; c < 61; ++c) {
    float tf[4], df[8];
    *(float4*)&tf[0] = *(const float4*)(&T[c * 64 + yy0]);
    *(float4*)&df[0] = *(const float4*)(&D[c * 128 + x0]);
    *(float4*)&df[4] = *(const float4*)(&D[c * 128 + x0 + 4]);
#pragma unroll
    for (int jy = 0; jy < 4; ++jy)
#pragma unroll
      for (int jx = 0; jx < 8; ++jx) acc[jy][jx] += tf[jy] * df[jx];
  }
  const float bo_ = bias[o];
  float* op = out + ((size_t)(b * 64 + o) * 128 + yh * 64) * 128;
#pragma unroll
  for (int jy = 0; jy < 4; ++jy) {
    *(float4*)(op + (yy0 + jy) * 128 + x0) =
        make_float4(acc[jy][0] + bo_, acc[jy][1] + bo_, acc[jy][2] + bo_, acc[jy][3] + bo_);
    *(float4*)(op + (yy0 + jy) * 128 + x0 + 4) =
        make_float4(acc[jy][4] + bo_, acc[jy][5] + bo_, acc[jy][6] + bo_, acc[jy][7] + bo_);
  }
}

extern "C" void kernel_launch(void* const* d_in, const int* in_sizes, int n_in,
                              void* d_out, int out_size, void* d_ws, size_t ws_size,
                              hipStream_t stream) {
  (void)in_sizes; (void)n_in; (void)out_size; (void)ws_size;
  const float* x = (const float*)d_in[0];
  const float* w = (const float*)d_in[1];
  const float* bias = (const float*)d_in[2];
  float* out = (float*)d_out;

  float* X1 = (float*)d_ws;
  float* X2 = X1 + 8126464;  // 1024*62*128
  float* F = X2 + 3872768;   // 1891*1024*2
  float* H = X1;             // X1 dead after k2'; same size

  k1_coldft<<<1024, 256, 0, stream>>>(x, X1);
  k2_rowdft<<<1024, 256, 0, stream>>>(X1, X2);
  k3_mix<<<946, 256, 0, stream>>>(X2, w, F);
  k4_invrow<<<992, 256, 0, stream>>>(F, H);
  k5_invcol<<<2048, 256, 0, stream>>>(H, bias, out);
}

// Round 4
// 373.814 us; speedup vs baseline: 1.1666x; 1.1666x over previous
//
#include <hip/hip_runtime.h>

// FFTConvNet: out[b,o] = IFFT2( M · sum_i X^[(b+8)%16, i] · W^[(o+32)%64, i] ) + bias[o]
// fftshift(no axes) shifts ALL dims -> batch roll 8, Cout roll 32; Cin rolls cancel.
// Disk mask fy^2+fx^2<=900. Hermitian half-spectrum: fy in [0,30] (31), fx in [-30,30] (61).
// f2 = fxp*31 + fy (fx-major), fxp = fx+30, NF = 1891.
// Pipeline: k0 (W^ -> bf16, separable 3x3 twiddles), k12 (colDFT+rowDFT+mask -> X2),
//           k3 (per-freq channel-mix GEMM, F stored [bo][f2]), k45 (inv-row DFT + Hermitian inv-col + bias).
// ws: Wt u32 [0, 7745536) ; X2 float [7745536, +3872768) ; F float [11618304, +3872768)
// total 61,964,288 bytes (<= 63,488,000 previously validated).

#define PI2_128 0.04908738521234052f  // 2*pi/128
#define NF 1891

__device__ inline unsigned bf16_rne(float v) {
  unsigned u = __float_as_uint(v);
  return (u + 0x7FFFu + ((u >> 16) & 1u)) >> 16;
}

// ---------------- K0: W^ precompute (bf16), separable 3x3 twiddles ----------------
// Wt[f2][i][o] = sum_{ky,kx} w[(o+32)&63][i][ky][kx] e^{-2pi i (fy ky + fx kx)/128}
__global__ __launch_bounds__(256) void k0_what(const float* __restrict__ w,
                                               unsigned* __restrict__ Wt) {
  const int tid = threadIdx.x;
  const int fxp = blockIdx.x >> 4;       // 0..60
  const int ig = blockIdx.x & 15;        // i-group
  const int il = tid >> 6;               // 0..3
  const int o = tid & 63;
  const int i = ig * 4 + il;
  const int op = (o + 32) & 63;
  const float* wp = w + (size_t)(op * 64 + i) * 9;
  float w9[9];
#pragma unroll
  for (int k = 0; k < 9; ++k) w9[k] = wp[k];

  const float fx = (float)(fxp - 30);
  float sn, cs;
  __sincosf(fx * PI2_128, &sn, &cs);
  const float e1x = cs, e1y = -sn;                       // e^{-2pi i fx/128}
  const float e2x = e1x * e1x - e1y * e1y, e2y = 2.f * e1x * e1y;
  float rxr[3], rxi[3];
#pragma unroll
  for (int ky = 0; ky < 3; ++ky) {
    rxr[ky] = w9[ky * 3] + w9[ky * 3 + 1] * e1x + w9[ky * 3 + 2] * e2x;
    rxi[ky] = w9[ky * 3 + 1] * e1y + w9[ky * 3 + 2] * e2y;
  }
  float pyx = 1.f, pyy = 0.f;                            // e^{-2pi i fy/128}
  const float stx = 0.9987954562f, sty = -0.04906767433f;
  unsigned* Wb = Wt + (size_t)(fxp * 31) * 4096 + i * 64 + o;
  for (int fy = 0; fy < 31; ++fy) {
    float p2x = pyx * pyx - pyy * pyy, p2y = 2.f * pyx * pyy;
    float Wre = rxr[0] + (rxr[1] * pyx - rxi[1] * pyy) + (rxr[2] * p2x - rxi[2] * p2y);
    float Wim = rxi[0] + (rxr[1] * pyy + rxi[1] * pyx) + (rxr[2] * p2y + rxi[2] * p2x);
    Wb[(size_t)fy * 4096] = bf16_rne(Wre) | (bf16_rne(Wim) << 16);
    float nx = pyx * stx - pyy * sty;
    pyy = pyx * sty + pyy * stx;
    pyx = nx;
  }
}

// ---------------- K12: fused column DFT + row DFT + disk mask ----------------
__global__ __launch_bounds__(256) void k12_fwd(const float* __restrict__ x,
                                               float* __restrict__ X2) {
  __shared__ __align__(16) float Bl[128 * 68];  // [x][c], c=2t+ri, stride 68
  const int bi = blockIdx.x;
  const int tid = threadIdx.x;
  const float* img = x + (size_t)bi * (128 * 128);

  // Phase A: column DFT (over y), thread = (t-pair, x-octet)
  {
    const int tg = tid >> 4;  // 0..15 -> t0 = 2*tg
    const int xg = tid & 15;  // 0..15 -> x0 = 8*xg
    const int t0 = tg * 2;
    const int x0 = xg * 8;
    float pc[2], ps[2], stc[2], sts[2];
#pragma unroll
    for (int f = 0; f < 2; ++f) {
      __sincosf((float)(t0 + f) * PI2_128, &sts[f], &stc[f]);
      pc[f] = 1.f;
      ps[f] = 0.f;
    }
    float o_r[2][8] = {{0.f}}, o_i[2][8] = {{0.f}};
    for (int y = 0; y < 128; ++y) {
      float4 v0 = *(const float4*)(img + y * 128 + x0);
      float4 v1 = *(const float4*)(img + y * 128 + x0 + 4);
      float vv[8] = {v0.x, v0.y, v0.z, v0.w, v1.x, v1.y, v1.z, v1.w};
#pragma unroll
      for (int f = 0; f < 2; ++f) {
        float c = pc[f], s = ps[f];
#pragma unroll
        for (int j = 0; j < 8; ++j) {
          o_r[f][j] += vv[j] * c;
          o_i[f][j] -= vv[j] * s;
        }
        pc[f] = c * stc[f] - s * sts[f];
        ps[f] = s * stc[f] + c * sts[f];
      }
    }
#pragma unroll
    for (int f = 0; f < 2; ++f) {
      int t = t0 + f;
      if (t < 31) {
#pragma unroll
        for (int j = 0; j < 8; ++j) {
          Bl[(x0 + j) * 68 + 2 * t] = o_r[f][j];
          Bl[(x0 + j) * 68 + 2 * t + 1] = o_i[f][j];
        }
      } else {  // t==31: zero-fill c=62,63 so phase B reads are clean
#pragma unroll
        for (int j = 0; j < 8; ++j) {
          Bl[(x0 + j) * 68 + 62] = 0.f;
          Bl[(x0 + j) * 68 + 63] = 0.f;
        }
      }
    }
  }
  __syncthreads();

  // Phase B: row DFT (over x) + mask, thread = (t-quad, fxp-pair)
  {
    const int tg = tid >> 5;   // 0..7  -> t0 = 4*tg
    const int fxg = tid & 31;  // 0..31 -> fxp0 = 2*fxg
    const int t0 = tg * 4;
    const int fxp0 = fxg * 2;
    float pc[2], ps[2], stc[2], sts[2];
#pragma unroll
    for (int j = 0; j < 2; ++j) {
      float fx = (float)(fxp0 + j - 30);
      __sincosf(fx * PI2_128, &sts[j], &stc[j]);
      pc[j] = 1.f;
      ps[j] = 0.f;
    }
    float o_r[4][2] = {{0.f}}, o_i[4][2] = {{0.f}};
    for (int xx = 0; xx < 128; ++xx) {
      float4 a0 = *(const float4*)(&Bl[xx * 68 + 8 * tg]);
      float4 a1 = *(const float4*)(&Bl[xx * 68 + 8 * tg + 4]);
      float ar[4] = {a0.x, a0.z, a1.x, a1.z};
      float ai[4] = {a0.y, a0.w, a1.y, a1.w};
#pragma unroll
      for (int j = 0; j < 2; ++j) {
        float c = pc[j], s = ps[j];
#pragma unroll
        for (int tt = 0; tt < 4; ++tt) {
          o_r[tt][j] += ar[tt] * c + ai[tt] * s;
          o_i[tt][j] += ai[tt] * c - ar[tt] * s;
        }
        pc[j] = c * stc[j] - s * sts[j];
        ps[j] = s * stc[j] + c * sts[j];
      }
    }
    float2* X2c = (float2*)X2 + (size_t)bi * NF;
#pragma unroll
    for (int tt = 0; tt < 4; ++tt) {
      int t = t0 + tt;
      if (t >= 31) continue;
#pragma unroll
      for (int j = 0; j < 2; ++j) {
        int fxp = fxp0 + j;
        if (fxp >= 61) continue;
        int fx = fxp - 30;
        bool keep = (t * t + fx * fx) <= 900;
        X2c[fxp * 31 + t] = keep ? make_float2(o_r[tt][j], o_i[tt][j]) : make_float2(0.f, 0.f);
      }
    }
  }
}

// ---------------- K3: per-frequency channel mix, W^ from global bf16 ----------------
// F[bo][f2] = sum_i X2[(b+8)&15, i][f2] * Wt[f2][i][o]
__global__ __launch_bounds__(256) void k3_mix(const float* __restrict__ X2,
                                              const unsigned* __restrict__ Wt,
                                              float* __restrict__ F) {
  __shared__ __align__(16) float2 X2t[4][16][16];  // [fi][il][b]
  __shared__ __align__(16) float2 Ws[4][16][64];   // [fi][il][o]
  const int tid = threadIdx.x;
  const int fxp = blockIdx.x >> 3;
  const int t0 = (blockIdx.x & 7) * 4;
  const int f2base = fxp * 31 + t0;
  const int fi_g = tid >> 6;  // wave's frequency
  const int lane = tid & 63;
  const int bt = lane >> 4;  // 0..3
  const int ot = lane & 15;  // 0..15
  float o_r[4][4] = {{0.f}}, o_i[4][4] = {{0.f}};

  for (int itile = 0; itile < 4; ++itile) {
    for (int j = tid; j < 1024; j += 256) {  // X2t: 4 fi * 16 il * 16 b
      int fi = j >> 8, rem = j & 255;
      int il = rem >> 4, b = rem & 15;
      int f2 = f2base + fi;
      if (f2 < NF) {
        int i = itile * 16 + il;
        int bs = (b + 8) & 15;  // batch fftshift
        X2t[fi][il][b] = ((const float2*)X2)[(size_t)(bs * 64 + i) * NF + f2];
      }
    }
    for (int j = tid; j < 1024; j += 256) {  // Ws: 4 fi * 16 il * 16 o-quads
      int fi = j >> 8, q = j & 255;
      int il = q >> 4, o4 = (q & 15) * 4;
      int f2 = f2base + fi;
      if (f2 < NF) {
        uint4 u = *(const uint4*)(Wt + (size_t)f2 * 4096 + (itile * 16 + il) * 64 + o4);
        unsigned uu[4] = {u.x, u.y, u.z, u.w};
#pragma unroll
        for (int k = 0; k < 4; ++k)
          Ws[fi][il][o4 + k] = make_float2(__uint_as_float(uu[k] << 16),
                                           __uint_as_float(uu[k] & 0xFFFF0000u));
      }
    }
    __syncthreads();
    for (int il = 0; il < 16; ++il) {
      float4 xa = *(const float4*)(&X2t[fi_g][il][bt * 4]);
      float4 xb = *(const float4*)(&X2t[fi_g][il][bt * 4 + 2]);
      float4 wa = *(const float4*)(&Ws[fi_g][il][ot * 4]);
      float4 wb = *(const float4*)(&Ws[fi_g][il][ot * 4 + 2]);
      float xr[4] = {xa.x, xa.z, xb.x, xb.z}, xi[4] = {xa.y, xa.w, xb.y, xb.w};
      float wr[4] = {wa.x, wa.z, wb.x, wb.z}, wi[4] = {wa.y, wa.w, wb.y, wb.w};
#pragma unroll
      for (int jb = 0; jb < 4; ++jb)
#pragma unroll
        for (int jo = 0; jo < 4; ++jo) {
          o_r[jb][jo] += xr[jb] * wr[jo] - xi[jb] * wi[jo];
          o_i[jb][jo] += xr[jb] * wi[jo] + xi[jb] * wr[jo];
        }
    }
    __syncthreads();
  }
  if (t0 + fi_g < 31) {
    int f2g = f2base + fi_g;
    float2* Fc = (float2*)F;
#pragma unroll
    for (int jb = 0; jb < 4; ++jb) {
      int b = bt * 4 + jb;
#pragma unroll
      for (int jo = 0; jo < 4; ++jo)
        Fc[(size_t)(b * 64 + ot * 4 + jo) * NF + f2g] = make_float2(o_r[jb][jo], o_i[jb][jo]);
    }
  }
}

// ---------------- K45: fused inverse row DFT + Hermitian inverse col DFT + bias ----------------
__global__ __launch_bounds__(256) void k45_out(const float* __restrict__ F,
                                               const float* __restrict__ bias,
                                               float* __restrict__ out) {
  __shared__ __align__(16) float2 tw[128];        // e^{+2pi i m/128}
  __shared__ __align__(16) float2 Fl[NF];         // 15128 B
  __shared__ __align__(16) float U[61 * 132];     // [c][x], stride 132 (16B-aligned rows)
  __shared__ __align__(16) float T[61 * 128];     // [c][y]
  const int b = blockIdx.x >> 6;
  const int o = blockIdx.x & 63;
  const int tid = threadIdx.x;
  const float2* Fc = (const float2*)F + (size_t)(b * 64 + o) * NF;

  if (tid < 128) {
    float sv, cv;
    __sincosf((float)tid * PI2_128, &sv, &cv);
    tw[tid] = make_float2(cv, sv);
  }
  for (int j = tid; j < NF; j += 256) Fl[j] = Fc[j];
  __syncthreads();

  // T table (uses tw)
  const float sc1 = 1.f / 16384.f;
  for (int j = tid; j < 61 * 128; j += 256) {
    int c = j >> 7, y = j & 127;
    float val;
    if (c == 0) val = sc1;
    else if (c <= 30) val = 2.f * sc1 * tw[(c * y) & 127].x;
    else val = -2.f * sc1 * tw[((c - 30) * y) & 127].y;
    T[j] = val;
  }

  // Phase 1: H(fy, x) = sum_fxp Fl[fxp*31+fy] e^{+2pi i (fxp-30) x/128}
  const int fy = tid & 31;   // 31 active
  const int xg = tid >> 5;   // 0..7 -> x0 = 16*xg
  const int x0 = xg * 16;
  if (fy < 31) {
    float pr[16], pi[16], sr[16], si[16];
#pragma unroll
    for (int j = 0; j < 16; ++j) {
      int xx = x0 + j;
      float2 st = tw[xx];
      sr[j] = st.x;
      si[j] = st.y;
      float2 p0 = tw[(-30 * xx) & 127];
      pr[j] = p0.x;
      pi[j] = p0.y;
    }
    float hr[16] = {0.f}, hi[16] = {0.f};
    for (int fxp = 0; fxp < 61; ++fxp) {
      float2 fv = Fl[fxp * 31 + fy];
#pragma unroll
      for (int j = 0; j < 16; ++j) {
        hr[j] += fv.x * pr[j] - fv.y * pi[j];
        hi[j] += fv.x * pi[j] + fv.y * pr[j];
        float np = pr[j] * sr[j] - pi[j] * si[j];
        pi[j] = pr[j] * si[j] + pi[j] * sr[j];
        pr[j] = np;
      }
    }
#pragma unroll
    for (int j = 0; j < 16; ++j) {
      U[fy * 132 + x0 + j] = hr[j];
      if (fy >= 1) U[(30 + fy) * 132 + x0 + j] = hi[j];
    }
  }
  __syncthreads();

  // Phase 2: out[y][x] = sum_c T[c][y] U[c][x] + bias
  const int yg = tid >> 4, xg2 = tid & 15;
  const int y0 = yg * 8, xo0 = xg2 * 8;
  float acc[8][8] = {{0.f}};
  for (int c = 0; c < 61; ++c) {
    float tf[8], uf[8];
    *(float4*)&tf[0] = *(const float4*)(&T[c * 128 + y0]);
    *(float4*)&tf[4] = *(const float4*)(&T[c * 128 + y0 + 4]);
    *(float4*)&uf[0] = *(const float4*)(&U[c * 132 + xo0]);
    *(float4*)&uf[4] = *(const float4*)(&U[c * 132 + xo0 + 4]);
#pragma unroll
    for (int jy = 0; jy < 8; ++jy)
#pragma unroll
      for (int jx = 0; jx < 8; ++jx) acc[jy][jx] += tf[jy] * uf[jx];
  }
  const float bo_ = bias[o];
  float* op = out + (size_t)(b * 64 + o) * 128 * 128;
#pragma unroll
  for (int jy = 0; jy < 8; ++jy) {
    *(float4*)(op + (y0 + jy) * 128 + xo0) =
        make_float4(acc[jy][0] + bo_, acc[jy][1] + bo_, acc[jy][2] + bo_, acc[jy][3] + bo_);
    *(float4*)(op + (y0 + jy) * 128 + xo0 + 4) =
        make_float4(acc[jy][4] + bo_, acc[jy][5] + bo_, acc[jy][6] + bo_, acc[jy][7] + bo_);
  }
}

extern "C" void kernel_launch(void* const* d_in, const int* in_sizes, int n_in,
                              void* d_out, int out_size, void* d_ws, size_t ws_size,
                              hipStream_t stream) {
  (void)in_sizes; (void)n_in; (void)out_size; (void)ws_size;
  const float* x = (const float*)d_in[0];
  const float* w = (const float*)d_in[1];
  const float* bias = (const float*)d_in[2];
  float* out = (float*)d_out;

  unsigned* Wt = (unsigned*)d_ws;                  // 7,745,536 u32
  float* X2 = (float*)d_ws + 7745536;              // 3,872,768 floats
  float* F = (float*)d_ws + 11618304;              // 3,872,768 floats

  k0_what<<<976, 256, 0, stream>>>(w, Wt);
  k12_fwd<<<1024, 256, 0, stream>>>(x, X2);
  k3_mix<<<488, 256, 0, stream>>>(X2, Wt, F);
  k45_out<<<1024, 256, 0, stream>>>(F, bias, out);
}

// Round 5
// 259.612 us; speedup vs baseline: 1.6798x; 1.4399x over previous
//
#include <hip/hip_runtime.h>

// FFTConvNet: out[b,o] = IFFT2( M · sum_i X^[(b+8)%16, i] · W^[(o+32)%64, i] ) + bias[o]
// fftshift(no axes) shifts ALL dims -> batch roll 8, Cout roll 32; Cin rolls cancel.
// Disk mask fy^2+fx^2<=900. Half-spectrum: fy(t) in [0,30] (31), fx in [-30,30] (61), f2 = fxp*31+t.
// Radix-4 folding everywhere: fold factors (-i)^{rk} (forward) / i^{rk} (inverse) are {±1,±i} = adds only.
// ws: Wt u32 [0, 7745536) ; X2 float [7745536, +3872768) ; F float [11618304, +3872768).

#define PI2_128 0.04908738521234052f  // 2*pi/128
#define NF 1891

// fxp list ordered by class r=(fxp+2)&3 (= fx mod 4): c0(15), c1(15), c2(16), c3(15), 3 dummies.
__device__ const int k_flist[64] = {
    2, 6, 10, 14, 18, 22, 26, 30, 34, 38, 42, 46, 50, 54, 58,
    3, 7, 11, 15, 19, 23, 27, 31, 35, 39, 43, 47, 51, 55, 59,
    0, 4, 8, 12, 16, 20, 24, 28, 32, 36, 40, 44, 48, 52, 56, 60,
    1, 5, 9, 13, 17, 21, 25, 29, 33, 37, 41, 45, 49, 53, 57,
    0, 0, 0};

__device__ inline unsigned bf16_rne(float v) {
  unsigned u = __float_as_uint(v);
  return (u + 0x7FFFu + ((u >> 16) & 1u)) >> 16;
}

// ---------------- K0: W^ precompute (bf16), separable 3x3 twiddles ----------------
__global__ __launch_bounds__(256) void k0_what(const float* __restrict__ w,
                                               unsigned* __restrict__ Wt) {
  const int tid = threadIdx.x;
  const int fxp = blockIdx.x >> 4;  // 0..60
  const int ig = blockIdx.x & 15;
  const int il = tid >> 6;
  const int o = tid & 63;
  const int i = ig * 4 + il;
  const int op = (o + 32) & 63;
  const float* wp = w + (size_t)(op * 64 + i) * 9;
  float w9[9];
#pragma unroll
  for (int k = 0; k < 9; ++k) w9[k] = wp[k];

  const float fx = (float)(fxp - 30);
  float sn, cs;
  __sincosf(fx * PI2_128, &sn, &cs);
  const float e1x = cs, e1y = -sn;
  const float e2x = e1x * e1x - e1y * e1y, e2y = 2.f * e1x * e1y;
  float rxr[3], rxi[3];
#pragma unroll
  for (int ky = 0; ky < 3; ++ky) {
    rxr[ky] = w9[ky * 3] + w9[ky * 3 + 1] * e1x + w9[ky * 3 + 2] * e2x;
    rxi[ky] = w9[ky * 3 + 1] * e1y + w9[ky * 3 + 2] * e2y;
  }
  float pyx = 1.f, pyy = 0.f;
  const float stx = 0.9987954562f, sty = -0.04906767433f;
  unsigned* Wb = Wt + (size_t)(fxp * 31) * 4096 + i * 64 + o;
  for (int fy = 0; fy < 31; ++fy) {
    float p2x = pyx * pyx - pyy * pyy, p2y = 2.f * pyx * pyy;
    float Wre = rxr[0] + (rxr[1] * pyx - rxi[1] * pyy) + (rxr[2] * p2x - rxi[2] * p2y);
    float Wim = rxi[0] + (rxr[1] * pyy + rxi[1] * pyx) + (rxr[2] * p2y + rxi[2] * p2x);
    Wb[(size_t)fy * 4096] = bf16_rne(Wre) | (bf16_rne(Wim) << 16);
    float nx = pyx * stx - pyy * sty;
    pyy = pyx * sty + pyy * stx;
    pyx = nx;
  }
}

// ---------------- K12: fused forward DFT (radix-4 folded both axes) ----------------
__global__ __launch_bounds__(256) void k12_fwd(const float* __restrict__ x,
                                               float* __restrict__ X2) {
  // Cls[(r*32+x)*68 + 2t(+1)]: 4 folded class-planes for phase B. 34816 B.
  __shared__ __align__(16) float Cls[8704];
  const int bi = blockIdx.x;
  const int tid = threadIdx.x;
  const float* img = x + (size_t)bi * 16384;

  // Phase A: y-DFT, radix-4 fold over y. Thread owns x in {xg,+32,+64,+96}, 4 freqs.
  {
    const int tg = tid >> 5;  // 0..7
    const int xg = tid & 31;
    const int t_[4] = {4 * tg, 4 * tg + 2, 2 * tg + 1, 2 * tg + 17};  // t=31 computed, discarded
    const float sgn = (tg & 1) ? 1.f : -1.f;  // (-i)^t for odd t: -i (t%4==1) / +i (t%4==3)
    float pc[4], ps[4], stc[4], sts[4];
#pragma unroll
    for (int f = 0; f < 4; ++f) {
      __sincosf((float)t_[f] * PI2_128, &sts[f], &stc[f]);
      pc[f] = 1.f;
      ps[f] = 0.f;
    }
    float ar_[4][4] = {{0.f}}, ai_[4][4] = {{0.f}};  // [freq][m]
    for (int y = 0; y < 32; ++y) {
      float v[4][4];
#pragma unroll
      for (int k = 0; k < 4; ++k)
#pragma unroll
        for (int m = 0; m < 4; ++m) v[k][m] = img[(y + 32 * k) * 128 + xg + 32 * m];
#pragma unroll
      for (int m = 0; m < 4; ++m) {
        float s = v[0][m] + v[2][m], d = v[0][m] - v[2][m];
        float s2 = v[1][m] + v[3][m], d2 = (v[1][m] - v[3][m]) * sgn;
        float a0 = s + s2, a1 = s - s2;
        ar_[0][m] += a0 * pc[0];
        ai_[0][m] -= a0 * ps[0];
        ar_[1][m] += a1 * pc[1];
        ai_[1][m] -= a1 * ps[1];
        ar_[2][m] += d * pc[2] + d2 * ps[2];
        ai_[2][m] += -d * ps[2] + d2 * pc[2];
        ar_[3][m] += d * pc[3] + d2 * ps[3];
        ai_[3][m] += -d * ps[3] + d2 * pc[3];
      }
#pragma unroll
      for (int f = 0; f < 4; ++f) {
        float c = pc[f], s = ps[f];
        pc[f] = c * stc[f] - s * sts[f];
        ps[f] = s * stc[f] + c * sts[f];
      }
    }
    // In-register x-butterfly (classes for phase B's fx fold), write 4 planes.
#pragma unroll
    for (int f = 0; f < 4; ++f) {
      int t = t_[f];
      float Ar = ar_[f][0] + ar_[f][2], Ai = ai_[f][0] + ai_[f][2];
      float Br = ar_[f][0] - ar_[f][2], Bi = ai_[f][0] - ai_[f][2];
      float Cr = ar_[f][1] + ar_[f][3], Ci = ai_[f][1] + ai_[f][3];
      float Dr = ar_[f][1] - ar_[f][3], Di = ai_[f][1] - ai_[f][3];
      float* base = Cls + xg * 68 + 2 * t;
      *(float2*)(base + 0 * 2176) = make_float2(Ar + Cr, Ai + Ci);  // r=0: A+C
      *(float2*)(base + 1 * 2176) = make_float2(Br + Di, Bi - Dr);  // r=1: B-iD
      *(float2*)(base + 2 * 2176) = make_float2(Ar - Cr, Ai - Ci);  // r=2: A-C
      *(float2*)(base + 3 * 2176) = make_float2(Br - Di, Bi + Dr);  // r=3: B+iD
    }
  }
  __syncthreads();

  // Phase B: x-DFT on folded planes (32 samples per freq) + disk mask.
  {
    const int tg2 = tid >> 5;  // t-quad: t = 4*tg2 + tt
    const int fxg = tid & 31;
    float accr[2][4] = {{0.f}}, acci[2][4] = {{0.f}};
    int fxp_[2], r_[2];
    float pc2[2], ps2[2], stc2[2], sts2[2];
#pragma unroll
    for (int u = 0; u < 2; ++u) {
      fxp_[u] = k_flist[2 * fxg + u];
      r_[u] = (fxp_[u] + 2) & 3;
      float fx = (float)(fxp_[u] - 30);
      __sincosf(fx * PI2_128, &sts2[u], &stc2[u]);
      pc2[u] = 1.f;
      ps2[u] = 0.f;
    }
    for (int xx = 0; xx < 32; ++xx) {
#pragma unroll
      for (int u = 0; u < 2; ++u) {
        const float* bp = Cls + (r_[u] * 32 + xx) * 68 + 8 * tg2;
        float4 za = *(const float4*)(bp);
        float4 zb = *(const float4*)(bp + 4);
        float zr[4] = {za.x, za.z, zb.x, zb.z};
        float zi[4] = {za.y, za.w, zb.y, zb.w};
        float c = pc2[u], s = ps2[u];
#pragma unroll
        for (int tt = 0; tt < 4; ++tt) {
          accr[u][tt] += zr[tt] * c + zi[tt] * s;
          acci[u][tt] += zi[tt] * c - zr[tt] * s;
        }
        pc2[u] = c * stc2[u] - s * sts2[u];
        ps2[u] = s * stc2[u] + c * sts2[u];
      }
    }
    float2* X2c = (float2*)X2 + (size_t)bi * NF;
#pragma unroll
    for (int u = 0; u < 2; ++u) {
      if (2 * fxg + u >= 61) continue;
      int fxp = fxp_[u], fx = fxp - 30;
#pragma unroll
      for (int tt = 0; tt < 4; ++tt) {
        int t = 4 * tg2 + tt;
        if (t >= 31) continue;
        bool keep = (t * t + fx * fx) <= 900;
        X2c[fxp * 31 + t] =
            keep ? make_float2(accr[u][tt], acci[u][tt]) : make_float2(0.f, 0.f);
      }
    }
  }
}

// ---------------- K3: per-frequency channel mix, W^ from global bf16 ----------------
__global__ __launch_bounds__(256) void k3_mix(const float* __restrict__ X2,
                                              const unsigned* __restrict__ Wt,
                                              float* __restrict__ F) {
  __shared__ __align__(16) float2 X2t[4][16][16];
  __shared__ __align__(16) float2 Ws[4][16][64];
  const int tid = threadIdx.x;
  const int fxp = blockIdx.x >> 3;
  const int t0 = (blockIdx.x & 7) * 4;
  const int f2base = fxp * 31 + t0;
  const int fi_g = tid >> 6;
  const int lane = tid & 63;
  const int bt = lane >> 4;
  const int ot = lane & 15;
  float o_r[4][4] = {{0.f}}, o_i[4][4] = {{0.f}};

  for (int itile = 0; itile < 4; ++itile) {
    for (int j = tid; j < 1024; j += 256) {
      int fi = j >> 8, rem = j & 255;
      int il = rem >> 4, b = rem & 15;
      int f2 = f2base + fi;
      if (f2 < NF) {
        int i = itile * 16 + il;
        int bs = (b + 8) & 15;
        X2t[fi][il][b] = ((const float2*)X2)[(size_t)(bs * 64 + i) * NF + f2];
      }
    }
    for (int j = tid; j < 1024; j += 256) {
      int fi = j >> 8, q = j & 255;
      int il = q >> 4, o4 = (q & 15) * 4;
      int f2 = f2base + fi;
      if (f2 < NF) {
        uint4 u = *(const uint4*)(Wt + (size_t)f2 * 4096 + (itile * 16 + il) * 64 + o4);
        unsigned uu[4] = {u.x, u.y, u.z, u.w};
#pragma unroll
        for (int k = 0; k < 4; ++k)
          Ws[fi][il][o4 + k] = make_float2(__uint_as_float(uu[k] << 16),
                                           __uint_as_float(uu[k] & 0xFFFF0000u));
      }
    }
    __syncthreads();
    for (int il = 0; il < 16; ++il) {
      float4 xa = *(const float4*)(&X2t[fi_g][il][bt * 4]);
      float4 xb = *(const float4*)(&X2t[fi_g][il][bt * 4 + 2]);
      float4 wa = *(const float4*)(&Ws[fi_g][il][ot * 4]);
      float4 wb = *(const float4*)(&Ws[fi_g][il][ot * 4 + 2]);
      float xr[4] = {xa.x, xa.z, xb.x, xb.z}, xi[4] = {xa.y, xa.w, xb.y, xb.w};
      float wr[4] = {wa.x, wa.z, wb.x, wb.z}, wi[4] = {wa.y, wa.w, wb.y, wb.w};
#pragma unroll
      for (int jb = 0; jb < 4; ++jb)
#pragma unroll
        for (int jo = 0; jo < 4; ++jo) {
          o_r[jb][jo] += xr[jb] * wr[jo] - xi[jb] * wi[jo];
          o_i[jb][jo] += xr[jb] * wi[jo] + xi[jb] * wr[jo];
        }
    }
    __syncthreads();
  }
  if (t0 + fi_g < 31) {
    int f2g = f2base + fi_g;
    float2* Fc = (float2*)F;
#pragma unroll
    for (int jb = 0; jb < 4; ++jb) {
      int b = bt * 4 + jb;
#pragma unroll
      for (int jo = 0; jo < 4; ++jo)
        Fc[(size_t)(b * 64 + ot * 4 + jo) * NF + f2g] = make_float2(o_r[jb][jo], o_i[jb][jo]);
    }
  }
}

// ---------------- K45: inverse (radix-4 fold in x, parity fold in y) + bias ----------------
__global__ __launch_bounds__(256) void k45_out(const float* __restrict__ F,
                                               const float* __restrict__ bias,
                                               float* __restrict__ out) {
  __shared__ __align__(16) float2 tw[128];  // e^{+2pi i m/128}
  __shared__ __align__(16) float U[61 * 132];
  __shared__ __align__(16) float TF[3904];  // union: Fl (phase<=1), then T
  const int b = blockIdx.x >> 6;
  const int o = blockIdx.x & 63;
  const int tid = threadIdx.x;
  float2* Fl = (float2*)TF;
  const float2* Fc = (const float2*)F + (size_t)(b * 64 + o) * NF;
  if (tid < 128) {
    float sv, cv;
    __sincosf((float)tid * PI2_128, &sv, &cv);
    tw[tid] = make_float2(cv, sv);
  }
  for (int j = tid; j < NF; j += 256) Fl[j] = Fc[j];
  __syncthreads();

  // Phase 1: inverse-x with output fold H(x+32k) = sum_r i^{rk} S_r
  {
    const int fy = tid & 31;
    const int xg = tid >> 3 >> 2;  // tid>>5: 0..7
    if (fy < 31) {
      float Sr[4][4] = {{0.f}}, Si[4][4] = {{0.f}};  // [r][j]
      float pr[4], pi[4], cr[4], ci[4];
#pragma unroll
      for (int j = 0; j < 4; ++j) {
        int xj = 4 * xg + j;
        float2 st = tw[xj];
        cr[j] = st.x;
        ci[j] = st.y;
        float2 p0 = tw[(-30 * xj) & 127];
        pr[j] = p0.x;
        pi[j] = p0.y;
      }
      const float2* Frow = Fl + fy;
      for (int f4 = 0; f4 < 60; f4 += 4) {
#pragma unroll
        for (int ss = 0; ss < 4; ++ss) {
          const int r = (ss + 2) & 3;  // fxp class pattern 2,3,0,1
          float2 fv = Frow[(f4 + ss) * 31];
#pragma unroll
          for (int j = 0; j < 4; ++j) {
            Sr[r][j] += fv.x * pr[j] - fv.y * pi[j];
            Si[r][j] += fv.x * pi[j] + fv.y * pr[j];
            float np = pr[j] * cr[j] - pi[j] * ci[j];
            pi[j] = pi[j] * cr[j] + pr[j] * ci[j];
            pr[j] = np;
          }
        }
      }
      {  // fxp = 60, class 2
        float2 fv = Frow[60 * 31];
#pragma unroll
        for (int j = 0; j < 4; ++j) {
          Sr[2][j] += fv.x * pr[j] - fv.y * pi[j];
          Si[2][j] += fv.x * pi[j] + fv.y * pr[j];
        }
      }
#pragma unroll
      for (int j = 0; j < 4; ++j) {
        int xj = 4 * xg + j;
        float Er = Sr[0][j] + Sr[2][j], Ei = Si[0][j] + Si[2][j];
        float Fr = Sr[0][j] - Sr[2][j], Fi = Si[0][j] - Si[2][j];
        float Gr = Sr[1][j] + Sr[3][j], Gi = Si[1][j] + Si[3][j];
        float Hr = Sr[1][j] - Sr[3][j], Hi = Si[1][j] - Si[3][j];
        U[fy * 132 + xj] = Er + Gr;
        U[fy * 132 + xj + 32] = Fr - Hi;   // F4 + iH
        U[fy * 132 + xj + 64] = Er - Gr;
        U[fy * 132 + xj + 96] = Fr + Hi;   // F4 - iH
        if (fy >= 1) {
          U[(30 + fy) * 132 + xj] = Ei + Gi;
          U[(30 + fy) * 132 + xj + 32] = Fi + Hr;
          U[(30 + fy) * 132 + xj + 64] = Ei - Gi;
          U[(30 + fy) * 132 + xj + 96] = Fi - Hr;
        }
      }
    }
  }
  __syncthreads();
  // Build T[c][y] (y<64) over Fl's dead storage.
  {
    const float sc1 = 1.f / 16384.f;
    float* T = TF;
    for (int j = tid; j < 61 * 64; j += 256) {
      int c = j >> 6, y = j & 63;
      float val;
      if (c == 0) val = sc1;
      else if (c <= 30) val = 2.f * sc1 * tw[(c * y) & 127].x;
      else val = -2.f * sc1 * tw[((c - 30) * y) & 127].y;
      T[j] = val;
    }
  }
  __syncthreads();
  // Phase 2: inverse-y with parity fold (even c -> P, odd c -> Q); out[y]=P+Q, out[y+64]=P-Q
  {
    const float* T = TF;
    const int yg = tid >> 5;
    const int xg = tid & 31;
    const int y0 = yg * 8, x0 = xg * 4;
    float Pa[8][4] = {{0.f}}, Qa[8][4] = {{0.f}};
    for (int c = 0; c < 60; c += 2) {
      float tf0[8], tf1[8], uf0[4], uf1[4];
      *(float4*)&tf0[0] = *(const float4*)(&T[c * 64 + y0]);
      *(float4*)&tf0[4] = *(const float4*)(&T[c * 64 + y0 + 4]);
      *(float4*)&tf1[0] = *(const float4*)(&T[(c + 1) * 64 + y0]);
      *(float4*)&tf1[4] = *(const float4*)(&T[(c + 1) * 64 + y0 + 4]);
      *(float4*)&uf0[0] = *(const float4*)(&U[c * 132 + x0]);
      *(float4*)&uf1[0] = *(const float4*)(&U[(c + 1) * 132 + x0]);
#pragma unroll
      for (int jy = 0; jy < 8; ++jy)
#pragma unroll
        for (int jx = 0; jx < 4; ++jx) {
          Pa[jy][jx] += tf0[jy] * uf0[jx];
          Qa[jy][jx] += tf1[jy] * uf1[jx];
        }
    }
    {  // c = 60 (even -> P)
      float tf0[8], uf0[4];
      *(float4*)&tf0[0] = *(const float4*)(&T[60 * 64 + y0]);
      *(float4*)&tf0[4] = *(const float4*)(&T[60 * 64 + y0 + 4]);
      *(float4*)&uf0[0] = *(const float4*)(&U[60 * 132 + x0]);
#pragma unroll
      for (int jy = 0; jy < 8; ++jy)
#pragma unroll
        for (int jx = 0; jx < 4; ++jx) Pa[jy][jx] += tf0[jy] * uf0[jx];
    }
    const float bo_ = bias[o];
    float* op = out + (size_t)(b * 64 + o) * 16384;
#pragma unroll
    for (int jy = 0; jy < 8; ++jy) {
      float4 lo, hi;
      lo.x = Pa[jy][0] + Qa[jy][0] + bo_;
      lo.y = Pa[jy][1] + Qa[jy][1] + bo_;
      lo.z = Pa[jy][2] + Qa[jy][2] + bo_;
      lo.w = Pa[jy][3] + Qa[jy][3] + bo_;
      hi.x = Pa[jy][0] - Qa[jy][0] + bo_;
      hi.y = Pa[jy][1] - Qa[jy][1] + bo_;
      hi.z = Pa[jy][2] - Qa[jy][2] + bo_;
      hi.w = Pa[jy][3] - Qa[jy][3] + bo_;
      *(float4*)(op + (y0 + jy) * 128 + x0) = lo;
      *(float4*)(op + (y0 + jy + 64) * 128 + x0) = hi;
    }
  }
}

extern "C" void kernel_launch(void* const* d_in, const int* in_sizes, int n_in,
                              void* d_out, int out_size, void* d_ws, size_t ws_size,
                              hipStream_t stream) {
  (void)in_sizes; (void)n_in; (void)out_size; (void)ws_size;
  const float* x = (const float*)d_in[0];
  const float* w = (const float*)d_in[1];
  const float* bias = (const float*)d_in[2];
  float* out = (float*)d_out;

  unsigned* Wt = (unsigned*)d_ws;
  float* X2 = (float*)d_ws + 7745536;
  float* F = (float*)d_ws + 11618304;

  k0_what<<<976, 256, 0, stream>>>(w, Wt);
  k12_fwd<<<1024, 256, 0, stream>>>(x, X2);
  k3_mix<<<488, 256, 0, stream>>>(X2, Wt, F);
  k45_out<<<1024, 256, 0, stream>>>(F, bias, out);
}